// Round 1
// baseline (390.712 us; speedup 1.0000x reference)
//
#include <hip/hip_runtime.h>
#include <math.h>

#define B_SZ 1024
#define K_SZ 24
#define H_SZ 64
#define NVIS 256

typedef float vfloat4 __attribute__((ext_vector_type(4)));  // native vec type
                                                            // (HIP float4 is a
                                                            // class; builtin
                                                            // rejects it)

// ---------------------------------------------------------------------------
// The conv input is a sum of per-(b,c) delta functions, so the op is a scatter
// of 5x5 weight patches into [B,24,64,64]. Floor = 402.6 MB output write
// (~64.5 us at the 6.25 TB/s the harness's own fill kernels achieve).
//
// R3 lesson: plane-grouping (PLANES=4) regressed — per-block barrier
// serialization costs more than prolog amortization saves. One plane per
// block, 24576 independent blocks, exactly 2 barriers each.
//
// R4 (this round): previous best (390.3 us) = 1.03 TB/s effective write BW,
// 6x off the plain-store fill ceiling. Per-block critical-path arithmetic
// (~1000 cyc, 8 blocks/CU resident) cannot account for it; the only
// structural difference vs a 6.25 TB/s fill kernel is the NON-TEMPORAL store
// flag, which bypasses the write-back L2 (the thing that buffers/combines the
// store stream). The L2-protection rationale defended only ~150 KB that L3
// re-serves for ~free. Theory: NT bypass caps write throughput. Change: plain
// stores (L2 write-back path). Everything else identical for clean A/B.
// ---------------------------------------------------------------------------

__global__ __launch_bounds__(256) void gs_prep(
    const float2* __restrict__ x,         // [B*K] (x,y)
    const int*    __restrict__ vis_b,     // [256]
    const int*    __restrict__ vis_k,     // [256]
    int*          __restrict__ spike_tab) // [B*K] packed y*64+x or -1
{
    __shared__ unsigned char killf[256];
    const int tid  = threadIdx.x;
    const int base = blockIdx.x * 256;
    const int bk   = base + tid;               // exactly B*K threads
    killf[tid] = 0;

    // spike position: match jnp.round((v+1.0)*0.5*(H-1)); rintf = half-to-even
    const float2 c = x[bk];
    const int cx = (int)rintf((c.x + 1.0f) * 0.5f * 63.0f);
    const int cy = (int)rintf((c.y + 1.0f) * 0.5f * 63.0f);
    // in-range AND torch quirk (x-coord != 0) => cx in [1,64)
    const bool ok = (cx >= 1) & (cx < H_SZ) & (cy >= 0) & (cy < H_SZ);
    int s = ok ? (cy * H_SZ + cx) : -1;

    // kill scatter: code == bk <=> this block's flag slot (racy same-value ok)
    const int code = vis_b[tid] * K_SZ + vis_k[tid];
    __syncthreads();                            // killf init complete
    const unsigned local = (unsigned)(code - base);
    if (local < 256u) killf[local] = 1;
    __syncthreads();
    if (killf[tid]) s = -1;
    spike_tab[bk] = s;
}

__global__ __launch_bounds__(256) void gs_main(
    const int*   __restrict__ spike_tab, // [B*K]
    const float* __restrict__ w,         // [K,K,5,5] OIHW, 600 floats per o
    float*       __restrict__ out)       // [B,K,64,64]
{
    __shared__ float tile[H_SZ * H_SZ];  // 16 KB; wave-limit -> 8 blocks/CU
    const int bid = blockIdx.x;
    const int b   = bid / K_SZ;
    const int o   = bid - b * K_SZ;
    const int tid = threadIdx.x;

    // ---- issue scatter-phase global loads first (latency overlaps zeroing)
    const int*   sp = spike_tab + b * K_SZ;
    const float* wo = w + o * (K_SZ * 25);
    int sv[3]; float wv[3]; int pp[3];
#pragma unroll
    for (int it = 0; it < 3; ++it) {
        const int t = tid + it * 256;
        sv[it] = -1;
        if (t < K_SZ * 25) {
            const int c = t / 25;
            pp[it] = t - c * 25;
            sv[it] = sp[c];        // 1-2 cache lines, lane-broadcast, L2-hit
            wv[it] = wo[t];        // fully coalesced, L2-hit
        }
    }

    // ---- zero the accumulation tile with b128 stores
    vfloat4* t4 = (vfloat4*)tile;
    const vfloat4 z = {0.f, 0.f, 0.f, 0.f};
#pragma unroll
    for (int r = 0; r < 4; ++r) t4[r * 256 + tid] = z;
    __syncthreads();

    // ---- scatter <=600 taps: out[i,j] += w[o,c,di,dj], i=y+2-di, j=x+2-dj
#pragma unroll
    for (int it = 0; it < 3; ++it) {
        const int s = sv[it];
        if (s >= 0) {
            const int y  = s >> 6;
            const int xx = s & 63;
            const int di = pp[it] / 5;
            const int dj = pp[it] - di * 5;
            const int i  = y + 2 - di;
            const int j  = xx + 2 - dj;
            if (((unsigned)i < H_SZ) & ((unsigned)j < H_SZ))
                atomicAdd(&tile[i * H_SZ + j], wv[it]);
        }
    }
    __syncthreads();

    // ---- stream the 16 KB plane out: coalesced float4 via the L2 write-back
    // path (NT bypass removed — R4 theory: NT capped write BW at ~1 TB/s)
    vfloat4* o4 = (vfloat4*)(out + ((size_t)bid << 12));
#pragma unroll
    for (int r = 0; r < 4; ++r) {
        const int idx = r * 256 + tid;
        o4[idx] = t4[idx];
    }
}

extern "C" void kernel_launch(void* const* d_in, const int* in_sizes, int n_in,
                              void* d_out, int out_size, void* d_ws, size_t ws_size,
                              hipStream_t stream) {
    const float2* x     = (const float2*)d_in[0];
    const float*  w     = (const float*)d_in[1];
    const int*    vis_b = (const int*)d_in[2];
    const int*    vis_k = (const int*)d_in[3];
    float*        out   = (float*)d_out;
    int*          spike_tab = (int*)d_ws;   // 24576 * 4 B = 96 KB scratch

    gs_prep<<<(B_SZ * K_SZ) / 256, 256, 0, stream>>>(x, vis_b, vis_k, spike_tab);
    gs_main<<<B_SZ * K_SZ, 256, 0, stream>>>(spike_tab, w, out);
}